// Round 8
// baseline (687.500 us; speedup 1.0000x reference)
//
#include <hip/hip_runtime.h>
#include <stdint.h>

#define BB 16
#define SS 2048
#define FF 512
#define DD 128
#define CC 1000

typedef __attribute__((ext_vector_type(8))) short bf16x8;
typedef __attribute__((ext_vector_type(4))) float f32x4;

__device__ __forceinline__ unsigned short f2bf(float f) {
  unsigned x;
  __builtin_memcpy(&x, &f, 4);
  x = x + 0x7FFFu + ((x >> 16) & 1u);
  return (unsigned short)(x >> 16);
}
__device__ __forceinline__ float bf2f(unsigned short u) {
  unsigned x = ((unsigned)u) << 16;
  float f;
  __builtin_memcpy(&f, &x, 4);
  return f;
}
__device__ __forceinline__ unsigned pk2(float a, float b) {
  return (unsigned)f2bf(a) | ((unsigned)f2bf(b) << 16);
}

// ---- workspace layout (bytes) ----
#define WS_WG   256        // float w[b][t] accumulator (131072 B)
#define WS_PK   131328     // packed mask bits uint32 [B][S][64] (8 MB)
#define WS_Q    8519936    // bf16 [B][S][128], q pre-scaled by D^-0.5
#define WS_K    16908544
#define WS_V    25297152
#define WS_WT   33685760   // bf16 WT[3][128][512]
#define WS_END  34078976

// ---------------- probe mask dtype + zero w accumulator ----------------
// flags[0] = 1 if mask is int32, 0 if byte. (All float tensors proven fp32.)
__global__ __launch_bounds__(256) void k_detect(const unsigned* __restrict__ mask,
                                                int* __restrict__ flags,
                                                float* __restrict__ wgl) {
  __shared__ unsigned red;
  const int tid = threadIdx.x;
  if (tid == 0) red = 0;
  __syncthreads();
  unsigned a = 0;
#pragma unroll
  for (int j = 0; j < 4; ++j) a |= mask[tid * 4 + j] & 0xFFFFFF00u;
  if (a) atomicOr(&red, 1u);
  __syncthreads();
  if (tid == 0) flags[0] = (red == 0) ? 1 : 0;
  for (int i = tid; i < BB * SS; i += 256) wgl[i] = 0.f;
}

// ---------------- pack mask (0/1) into bitmask ----------------
__global__ __launch_bounds__(256) void k_pack(const void* __restrict__ mask,
                                              const int* __restrict__ flags,
                                              unsigned* __restrict__ pk) {
  const int tid = threadIdx.x;
  const long long base = (long long)blockIdx.x * 2048;
  const bool isInt = flags[0] != 0;
#pragma unroll
  for (int it = 0; it < 8; ++it) {
    long long e = base + it * 256 + tid;
    int val;
    if (isInt) val = ((const int*)mask)[e];
    else       val = ((const unsigned char*)mask)[e];
    unsigned long long bal = __ballot(val != 0);
    if ((tid & 31) == 0)
      pk[e >> 5] = (unsigned)((tid & 63) ? (bal >> 32) : bal);
  }
}

// ---------------- transpose+convert Wq/Wk/Wv fp32[512][128] -> bf16 WT[3][128][512] --
__global__ __launch_bounds__(256) void k_wt(const float* __restrict__ Wq,
                                            const float* __restrict__ Wk,
                                            const float* __restrict__ Wv,
                                            unsigned short* __restrict__ wt) {
  int idx = blockIdx.x * 256 + threadIdx.x;  // 0..196607
  int ty = idx >> 16;
  int o = idx & 65535;
  int d = o >> 9, f = o & 511;
  const float* W = ty == 0 ? Wq : (ty == 1 ? Wk : Wv);
  wt[idx] = f2bf(W[f * DD + d]);
}

// ---------------- QKV projection: x[32768,512]fp32 @ W -> q/k/v [B*S,128] bf16 ------
// 128x128 tile, 4 waves each 64x64 (4x4 of 16x16x32), BK=32. fp32 x converted in regs.
__global__ __launch_bounds__(256) void k_proj(const float* __restrict__ xg,
                                              const unsigned short* __restrict__ wtg,
                                              const float* __restrict__ bq,
                                              const float* __restrict__ bk,
                                              const float* __restrict__ bv,
                                              unsigned short* __restrict__ qo,
                                              unsigned short* __restrict__ ko,
                                              unsigned short* __restrict__ vo) {
  __shared__ __align__(16) char lA[8192];  // 128 rows x 64B, chunk swizzle c^((r>>1)&3)
  __shared__ __align__(16) char lB[8192];
  const int tid = threadIdx.x;
  const int lane = tid & 63;
  const int wv = tid >> 6;
  const int colL = lane & 15, quad = lane >> 4;
  const int blk = blockIdx.x, ty = blockIdx.y;
  const float* bias = ty == 0 ? bq : (ty == 1 ? bk : bv);
  unsigned short* outp = ty == 0 ? qo : (ty == 1 ? ko : vo);
  const float scale = ty == 0 ? 0.08838834764831845f : 1.0f;
  const unsigned short* wbase = wtg + (size_t)ty * 65536;
  const int m0 = (wv & 1) * 64, n0 = (wv >> 1) * 64;

  f32x4 acc[4][4];
  const f32x4 z4 = {0.f, 0.f, 0.f, 0.f};
#pragma unroll
  for (int mi = 0; mi < 4; ++mi)
#pragma unroll
    for (int ni = 0; ni < 4; ++ni) acc[mi][ni] = z4;

  for (int ic = 0; ic < 16; ++ic) {
    const int k0 = ic * 32;
    uint4 va[2], vb[2];
#pragma unroll
    for (int rr = 0; rr < 2; ++rr) {
      int p = rr * 256 + tid;
      int row = p >> 2, c = p & 3;
      const float* xp = xg + (size_t)(blk * 128 + row) * FF + k0 + c * 8;
      float4 x0 = *(const float4*)xp;
      float4 x1 = *(const float4*)(xp + 4);
      va[rr].x = pk2(x0.x, x0.y); va[rr].y = pk2(x0.z, x0.w);
      va[rr].z = pk2(x1.x, x1.y); va[rr].w = pk2(x1.z, x1.w);
      vb[rr] = *(const uint4*)(wbase + (size_t)row * FF + k0 + c * 8);
    }
    __syncthreads();  // previous iteration's LDS reads complete
#pragma unroll
    for (int rr = 0; rr < 2; ++rr) {
      int p = rr * 256 + tid;
      int row = p >> 2, c = p & 3;
      int phys = c ^ ((row >> 1) & 3);
      *(uint4*)(lA + row * 64 + phys * 16) = va[rr];
      *(uint4*)(lB + row * 64 + phys * 16) = vb[rr];
    }
    __syncthreads();
    bf16x8 af[4], bfr[4];
#pragma unroll
    for (int mi = 0; mi < 4; ++mi) {
      int ar = m0 + mi * 16 + colL;
      int phys = quad ^ ((ar >> 1) & 3);
      af[mi] = *(const bf16x8*)(lA + ar * 64 + phys * 16);
    }
#pragma unroll
    for (int ni = 0; ni < 4; ++ni) {
      int br = n0 + ni * 16 + colL;
      int phys = quad ^ ((br >> 1) & 3);
      bfr[ni] = *(const bf16x8*)(lB + br * 64 + phys * 16);
    }
#pragma unroll
    for (int mi = 0; mi < 4; ++mi)
#pragma unroll
      for (int ni = 0; ni < 4; ++ni)
        acc[mi][ni] = __builtin_amdgcn_mfma_f32_16x16x32_bf16(af[mi], bfr[ni], acc[mi][ni], 0, 0, 0);
  }
#pragma unroll
  for (int ni = 0; ni < 4; ++ni) {
    int col = n0 + ni * 16 + colL;
    float bval = bias[col];
#pragma unroll
    for (int mi = 0; mi < 4; ++mi) {
#pragma unroll
      for (int r = 0; r < 4; ++r) {
        int row = blk * 128 + m0 + mi * 16 + quad * 4 + r;  // C/D: row=quad*4+reg, col=lane&15
        float val = (acc[mi][ni][r] + bval) * scale;
        outp[(size_t)row * DD + col] = f2bf(val);
      }
    }
  }
}

// ---------------- attention column-sum tile step ----------------
// Pass1 (P1=true): accumulate Z per q-row. Pass2: colsum of exp(l)/Z.
template <bool P1>
__device__ __forceinline__ void attn_tiles2(const char* kt, const unsigned* maskw,
                                            const bf16x8 (&qf)[2][4], float (&z)[2][4],
                                            const float (&zinv)[2][4], float* wacc,
                                            int t0, int colL, int quad, int wv) {
#pragma unroll
  for (int nt = 0; nt < 4; ++nt) {
    int rb = nt * 16 + colL;  // K-tile row (t within tile), B-frag n = colL
    bf16x8 bb[4];
#pragma unroll
    for (int kk = 0; kk < 4; ++kk) {
      int phys = (kk * 4 + quad) ^ (rb & 7);
      bb[kk] = *(const bf16x8*)(kt + rb * 256 + phys * 16);
    }
    int tcol = t0 + nt * 16 + colL;
    int wword = tcol >> 5, wbit = tcol & 31;
    float cs = 0.f;
#pragma unroll
    for (int mi = 0; mi < 2; ++mi) {
      f32x4 acc = {0.f, 0.f, 0.f, 0.f};
      acc = __builtin_amdgcn_mfma_f32_16x16x32_bf16(qf[mi][0], bb[0], acc, 0, 0, 0);
      acc = __builtin_amdgcn_mfma_f32_16x16x32_bf16(qf[mi][1], bb[1], acc, 0, 0, 0);
      acc = __builtin_amdgcn_mfma_f32_16x16x32_bf16(qf[mi][2], bb[2], acc, 0, 0, 0);
      acc = __builtin_amdgcn_mfma_f32_16x16x32_bf16(qf[mi][3], bb[3], acc, 0, 0, 0);
      int rbase = wv * 32 + mi * 16 + quad * 4;
#pragma unroll
      for (int r = 0; r < 4; ++r) {
        unsigned mw = maskw[(rbase + r) * 64 + wword];
        float l = fminf(acc[r], 80.0f);
        float e = ((mw >> wbit) & 1u) ? 0.f : __expf(l);
        if (P1) z[mi][r] += e;
        else cs += e * zinv[mi][r];
      }
    }
    if (!P1) {
      cs += __shfl_xor(cs, 16, 64);
      cs += __shfl_xor(cs, 32, 64);
      if (quad == 0) atomicAdd(&wacc[tcol], cs);
    }
  }
}

__global__ __launch_bounds__(256) void k_attn(const unsigned short* __restrict__ qg,
                                              const unsigned short* __restrict__ kg,
                                              const unsigned* __restrict__ pk,
                                              float* __restrict__ wglob) {
  __shared__ __align__(16) char kt[16384];       // 64 rows x 256B, chunk swizzle c^(r&7)
  __shared__ __align__(16) unsigned maskw[8192]; // 128 rows x 64 words (32 KB)
  __shared__ float wacc[SS];
  const int tid = threadIdx.x;
  const int lane = tid & 63, wv = tid >> 6;
  const int colL = lane & 15, quad = lane >> 4;
  const int row0 = blockIdx.x * 128;
  const int b = blockIdx.y;

  for (int i = tid; i < SS; i += 256) wacc[i] = 0.f;
  {
    const uint4* src = (const uint4*)(pk + ((size_t)b * SS + row0) * 64);
    uint4* dst = (uint4*)maskw;
    for (int i = tid; i < 2048; i += 256) dst[i] = src[i];
  }
  bf16x8 qf[2][4];
#pragma unroll
  for (int mi = 0; mi < 2; ++mi) {
    int qrow = row0 + wv * 32 + mi * 16 + colL;   // A-frag m = colL
    const unsigned short* qp = qg + ((size_t)b * SS + qrow) * DD + quad * 8;
#pragma unroll
    for (int kk = 0; kk < 4; ++kk) qf[mi][kk] = *(const bf16x8*)(qp + kk * 32);
  }
  __syncthreads();

  float z[2][4] = {{0.f, 0.f, 0.f, 0.f}, {0.f, 0.f, 0.f, 0.f}};
  float zinv[2][4] = {{0.f, 0.f, 0.f, 0.f}, {0.f, 0.f, 0.f, 0.f}};

  // pass 1: Z per row
  for (int t0 = 0; t0 < SS; t0 += 64) {
    uint4 kreg[4];
#pragma unroll
    for (int rr = 0; rr < 4; ++rr) {
      int p = rr * 256 + tid;
      int row = p >> 4, c = p & 15;
      kreg[rr] = *(const uint4*)(kg + ((size_t)b * SS + t0 + row) * DD + c * 8);
    }
    __syncthreads();
#pragma unroll
    for (int rr = 0; rr < 4; ++rr) {
      int p = rr * 256 + tid;
      int row = p >> 4, c = p & 15;
      int phys = c ^ (row & 7);
      *(uint4*)(kt + row * 256 + phys * 16) = kreg[rr];
    }
    __syncthreads();
    attn_tiles2<true>(kt, maskw, qf, z, zinv, wacc, t0, colL, quad, wv);
  }
  // combine Z across the 16 lanes of each quad
#pragma unroll
  for (int mi = 0; mi < 2; ++mi)
#pragma unroll
    for (int r = 0; r < 4; ++r) {
      float s = z[mi][r];
      s += __shfl_xor(s, 1, 64);
      s += __shfl_xor(s, 2, 64);
      s += __shfl_xor(s, 4, 64);
      s += __shfl_xor(s, 8, 64);
      zinv[mi][r] = 1.0f / fmaxf(s, 1e-30f);
    }
  // pass 2: column sums of P
  for (int t0 = 0; t0 < SS; t0 += 64) {
    uint4 kreg[4];
#pragma unroll
    for (int rr = 0; rr < 4; ++rr) {
      int p = rr * 256 + tid;
      int row = p >> 4, c = p & 15;
      kreg[rr] = *(const uint4*)(kg + ((size_t)b * SS + t0 + row) * DD + c * 8);
    }
    __syncthreads();
#pragma unroll
    for (int rr = 0; rr < 4; ++rr) {
      int p = rr * 256 + tid;
      int row = p >> 4, c = p & 15;
      int phys = c ^ (row & 7);
      *(uint4*)(kt + row * 256 + phys * 16) = kreg[rr];
    }
    __syncthreads();
    attn_tiles2<false>(kt, maskw, qf, z, zinv, wacc, t0, colL, quad, wv);
  }
  __syncthreads();
  for (int i = tid; i < SS; i += 256)
    atomicAdd(&wglob[(size_t)b * SS + i], wacc[i]);
}

// ---------------- finalize: y = (w/S) @ V ; out = y @ Wl + bl  (fp32 out!) ----------
__global__ __launch_bounds__(256) void k_final(const float* __restrict__ wgl,
                                               const unsigned short* __restrict__ vg,
                                               const float* __restrict__ Wl,
                                               const float* __restrict__ bl,
                                               float* __restrict__ outp) {
  __shared__ float y[DD];
  __shared__ float tmp[DD];
  const int tid = threadIdx.x;
  const int b = blockIdx.x;
  const int d = tid & 127, half = tid >> 7;
  float p = 0.f;
  const float* wrow = wgl + (size_t)b * SS + half * 1024;
  const unsigned short* vrow = vg + ((size_t)b * SS + half * 1024) * DD + d;
#pragma unroll 8
  for (int t = 0; t < 1024; ++t) p += wrow[t] * bf2f(vrow[(size_t)t * DD]);
  if (half) tmp[d] = p;
  __syncthreads();
  if (!half) y[d] = (p + tmp[d]) * (1.0f / 2048.0f);
  __syncthreads();
  for (int c = tid; c < CC; c += 256) {
    float a = bl[c];
#pragma unroll 16
    for (int dd = 0; dd < DD; ++dd) a += y[dd] * Wl[dd * CC + c];
    outp[b * CC + c] = a;   // fp32 output
  }
}

extern "C" void kernel_launch(void* const* d_in, const int* in_sizes, int n_in,
                              void* d_out, int out_size, void* d_ws, size_t ws_size,
                              hipStream_t stream) {
  const void* ptr[10];
  for (int i = 0; i < 10; ++i) ptr[i] = (i < n_in) ? d_in[i] : nullptr;
  if (n_in == 10) {  // size-based slot matching (no-op under dict order)
    const void *px = 0, *pm = 0, *pWl = 0, *pbl = 0;
    const void* pW[3] = {0, 0, 0};
    const void* pb[3] = {0, 0, 0};
    int nW = 0, nb = 0;
    for (int i = 0; i < 10; ++i) {
      int s = in_sizes[i];
      if (s == 16777216) px = d_in[i];
      else if (s == 67108864) pm = d_in[i];
      else if (s == 128000) pWl = d_in[i];
      else if (s == 1000) pbl = d_in[i];
      else if (s == 65536 && nW < 3) pW[nW++] = d_in[i];
      else if (s == 128 && nb < 3) pb[nb++] = d_in[i];
    }
    if (px && pm && pWl && pbl && nW == 3 && nb == 3) {
      ptr[0] = px; ptr[1] = pm;
      ptr[2] = pW[0]; ptr[3] = pb[0];
      ptr[4] = pW[1]; ptr[5] = pb[1];
      ptr[6] = pW[2]; ptr[7] = pb[2];
      ptr[8] = pWl; ptr[9] = pbl;
    }
  }
  char* ws = (char*)d_ws;
  if (ws_size < (size_t)WS_END) return;
  int* flags = (int*)ws;
  float* wg = (float*)(ws + WS_WG);
  unsigned* pk = (unsigned*)(ws + WS_PK);
  unsigned short* q  = (unsigned short*)(ws + WS_Q);
  unsigned short* k  = (unsigned short*)(ws + WS_K);
  unsigned short* v  = (unsigned short*)(ws + WS_V);
  unsigned short* wt = (unsigned short*)(ws + WS_WT);

  k_detect<<<1, 256, 0, stream>>>((const unsigned*)ptr[1], flags, wg);
  k_pack<<<32768, 256, 0, stream>>>(ptr[1], flags, pk);
  k_wt<<<768, 256, 0, stream>>>((const float*)ptr[2], (const float*)ptr[4],
                                (const float*)ptr[6], wt);
  k_proj<<<dim3(256, 3), 256, 0, stream>>>((const float*)ptr[0], wt,
                                           (const float*)ptr[3], (const float*)ptr[5],
                                           (const float*)ptr[7], q, k, v);
  k_attn<<<dim3(16, 16), 256, 0, stream>>>(q, k, pk, wg);
  k_final<<<16, 256, 0, stream>>>(wg, v, (const float*)ptr[8], (const float*)ptr[9],
                                  (float*)d_out);
}

// Round 9
// 611.159 us; speedup vs baseline: 1.1249x; 1.1249x over previous
//
#include <hip/hip_runtime.h>
#include <stdint.h>

#define BB 16
#define SS 2048
#define FF 512
#define DD 128
#define CC 1000

typedef __attribute__((ext_vector_type(8))) short bf16x8;
typedef __attribute__((ext_vector_type(4))) float f32x4;

__device__ __forceinline__ unsigned short f2bf(float f) {
  unsigned x;
  __builtin_memcpy(&x, &f, 4);
  x = x + 0x7FFFu + ((x >> 16) & 1u);
  return (unsigned short)(x >> 16);
}
__device__ __forceinline__ float bf2f(unsigned short u) {
  unsigned x = ((unsigned)u) << 16;
  float f;
  __builtin_memcpy(&f, &x, 4);
  return f;
}
__device__ __forceinline__ unsigned pk2(float a, float b) {
  return (unsigned)f2bf(a) | ((unsigned)f2bf(b) << 16);
}

// ---- workspace layout (bytes) ----
#define WS_WG   256        // float wg[16][2048]
#define WS_ZG   131328     // float zg[16][2048]
#define WS_YG   262400     // float yg[16][128]
#define WS_PK   270592     // packed mask bits uint32 [B][S][64] (8 MB)
#define WS_Q    8659200    // bf16 [B][S][128], q pre-scaled by D^-0.5
#define WS_K    17047808
#define WS_V    25436416
#define WS_WT   33825024   // bf16 WT[3][128][512]
#define WS_END  34218240

// ---------------- probe mask dtype + zero accumulators ----------------
__global__ __launch_bounds__(256) void k_detect(const unsigned* __restrict__ mask,
                                                int* __restrict__ flags,
                                                float* __restrict__ wgl,
                                                float* __restrict__ zgl,
                                                float* __restrict__ ygl) {
  __shared__ unsigned red;
  const int tid = threadIdx.x;
  if (tid == 0) red = 0;
  __syncthreads();
  unsigned a = 0;
#pragma unroll
  for (int j = 0; j < 4; ++j) a |= mask[tid * 4 + j] & 0xFFFFFF00u;
  if (a) atomicOr(&red, 1u);
  __syncthreads();
  if (tid == 0) flags[0] = (red == 0) ? 1 : 0;   // 1 = int32 mask, 0 = byte
  for (int i = tid; i < BB * SS; i += 256) { wgl[i] = 0.f; zgl[i] = 0.f; }
  for (int i = tid; i < BB * DD; i += 256) ygl[i] = 0.f;
}

// ---------------- pack mask (0/1) into bitmask ----------------
__global__ __launch_bounds__(256) void k_pack(const void* __restrict__ mask,
                                              const int* __restrict__ flags,
                                              unsigned* __restrict__ pk) {
  const int tid = threadIdx.x;
  const long long base = (long long)blockIdx.x * 2048;
  const bool isInt = flags[0] != 0;
#pragma unroll
  for (int it = 0; it < 8; ++it) {
    long long e = base + it * 256 + tid;
    int val;
    if (isInt) val = ((const int*)mask)[e];
    else       val = ((const unsigned char*)mask)[e];
    unsigned long long bal = __ballot(val != 0);
    if ((tid & 31) == 0)
      pk[e >> 5] = (unsigned)((tid & 63) ? (bal >> 32) : bal);
  }
}

// ---------------- transpose+convert Wq/Wk/Wv fp32[512][128] -> bf16 WT[3][128][512] --
__global__ __launch_bounds__(256) void k_wt(const float* __restrict__ Wq,
                                            const float* __restrict__ Wk,
                                            const float* __restrict__ Wv,
                                            unsigned short* __restrict__ wt) {
  int idx = blockIdx.x * 256 + threadIdx.x;
  int ty = idx >> 16;
  int o = idx & 65535;
  int d = o >> 9, f = o & 511;
  const float* W = ty == 0 ? Wq : (ty == 1 ? Wk : Wv);
  wt[idx] = f2bf(W[f * DD + d]);
}

// ---------------- QKV projection (unchanged from r8) ----------------
__global__ __launch_bounds__(256) void k_proj(const float* __restrict__ xg,
                                              const unsigned short* __restrict__ wtg,
                                              const float* __restrict__ bq,
                                              const float* __restrict__ bk,
                                              const float* __restrict__ bv,
                                              unsigned short* __restrict__ qo,
                                              unsigned short* __restrict__ ko,
                                              unsigned short* __restrict__ vo) {
  __shared__ __align__(16) char lA[8192];
  __shared__ __align__(16) char lB[8192];
  const int tid = threadIdx.x;
  const int lane = tid & 63;
  const int wv = tid >> 6;
  const int colL = lane & 15, quad = lane >> 4;
  const int blk = blockIdx.x, ty = blockIdx.y;
  const float* bias = ty == 0 ? bq : (ty == 1 ? bk : bv);
  unsigned short* outp = ty == 0 ? qo : (ty == 1 ? ko : vo);
  const float scale = ty == 0 ? 0.08838834764831845f : 1.0f;
  const unsigned short* wbase = wtg + (size_t)ty * 65536;
  const int m0 = (wv & 1) * 64, n0 = (wv >> 1) * 64;

  f32x4 acc[4][4];
  const f32x4 z4 = {0.f, 0.f, 0.f, 0.f};
#pragma unroll
  for (int mi = 0; mi < 4; ++mi)
#pragma unroll
    for (int ni = 0; ni < 4; ++ni) acc[mi][ni] = z4;

  for (int ic = 0; ic < 16; ++ic) {
    const int k0 = ic * 32;
    uint4 va[2], vb[2];
#pragma unroll
    for (int rr = 0; rr < 2; ++rr) {
      int p = rr * 256 + tid;
      int row = p >> 2, c = p & 3;
      const float* xp = xg + (size_t)(blk * 128 + row) * FF + k0 + c * 8;
      float4 x0 = *(const float4*)xp;
      float4 x1 = *(const float4*)(xp + 4);
      va[rr].x = pk2(x0.x, x0.y); va[rr].y = pk2(x0.z, x0.w);
      va[rr].z = pk2(x1.x, x1.y); va[rr].w = pk2(x1.z, x1.w);
      vb[rr] = *(const uint4*)(wbase + (size_t)row * FF + k0 + c * 8);
    }
    __syncthreads();
#pragma unroll
    for (int rr = 0; rr < 2; ++rr) {
      int p = rr * 256 + tid;
      int row = p >> 2, c = p & 3;
      int phys = c ^ ((row >> 1) & 3);
      *(uint4*)(lA + row * 64 + phys * 16) = va[rr];
      *(uint4*)(lB + row * 64 + phys * 16) = vb[rr];
    }
    __syncthreads();
    bf16x8 af[4], bfr[4];
#pragma unroll
    for (int mi = 0; mi < 4; ++mi) {
      int ar = m0 + mi * 16 + colL;
      int phys = quad ^ ((ar >> 1) & 3);
      af[mi] = *(const bf16x8*)(lA + ar * 64 + phys * 16);
    }
#pragma unroll
    for (int ni = 0; ni < 4; ++ni) {
      int br = n0 + ni * 16 + colL;
      int phys = quad ^ ((br >> 1) & 3);
      bfr[ni] = *(const bf16x8*)(lB + br * 64 + phys * 16);
    }
#pragma unroll
    for (int mi = 0; mi < 4; ++mi)
#pragma unroll
      for (int ni = 0; ni < 4; ++ni)
        acc[mi][ni] = __builtin_amdgcn_mfma_f32_16x16x32_bf16(af[mi], bfr[ni], acc[mi][ni], 0, 0, 0);
  }
#pragma unroll
  for (int ni = 0; ni < 4; ++ni) {
    int col = n0 + ni * 16 + colL;
    float bval = bias[col];
#pragma unroll
    for (int mi = 0; mi < 4; ++mi) {
#pragma unroll
      for (int r = 0; r < 4; ++r) {
        int row = blk * 128 + m0 + mi * 16 + quad * 4 + r;
        float val = (acc[mi][ni][r] + bval) * scale;
        outp[(size_t)row * DD + col] = f2bf(val);
      }
    }
  }
}

// ---------------- attention: two kernels over (sb, tc, b) ----------------
// PZ=true: accumulate Z[b][s] partials. PZ=false: colsum exp/Z -> wg[b][t].
// Per block: 128 q-rows x 256 t-cols (4 k-tiles of 64). LDS ~22 KB.
template <bool PZ>
__global__ __launch_bounds__(256) void k_attn2(const unsigned short* __restrict__ qg,
                                               const unsigned short* __restrict__ kg,
                                               const unsigned* __restrict__ pk,
                                               float* __restrict__ zg,
                                               float* __restrict__ wg) {
  __shared__ __align__(16) char kt[16384];   // 64 rows x 256B, chunk swizzle c^(r&7)
  __shared__ unsigned maskt[128 * 9];        // stride 9 words -> quad offsets hit distinct banks
  __shared__ float wacc[256];
  const int tid = threadIdx.x;
  const int lane = tid & 63, wv = tid >> 6;
  const int colL = lane & 15, quad = lane >> 4;
  const int row0 = blockIdx.x * 128;
  const int tc = blockIdx.y;                 // 8 chunks of 256 t
  const int b = blockIdx.z;
  const int tbase = tc * 256;

  // stage mask words for rows x t-chunk
  for (int i = tid; i < 1024; i += 256) {
    int row = i >> 3, w = i & 7;
    maskt[row * 9 + w] = pk[((size_t)b * SS + row0 + row) * 64 + tc * 8 + w];
  }
  if (!PZ) wacc[tid] = 0.f;

  bf16x8 qf[2][4];
#pragma unroll
  for (int mi = 0; mi < 2; ++mi) {
    int qrow = row0 + wv * 32 + mi * 16 + colL;   // A-frag m = colL
    const unsigned short* qp = qg + ((size_t)b * SS + qrow) * DD + quad * 8;
#pragma unroll
    for (int kk = 0; kk < 4; ++kk) qf[mi][kk] = *(const bf16x8*)(qp + kk * 32);
  }
  float z[2][4] = {{0.f, 0.f, 0.f, 0.f}, {0.f, 0.f, 0.f, 0.f}};
  float zinv[2][4];
  if (!PZ) {
#pragma unroll
    for (int mi = 0; mi < 2; ++mi)
#pragma unroll
      for (int r = 0; r < 4; ++r) {
        int row = row0 + wv * 32 + mi * 16 + quad * 4 + r;
        zinv[mi][r] = 1.0f / fmaxf(zg[(size_t)b * SS + row], 1e-30f);
      }
  }

  for (int kt0 = 0; kt0 < 4; ++kt0) {
    const int t0 = tbase + kt0 * 64;
    uint4 kreg[4];
#pragma unroll
    for (int rr = 0; rr < 4; ++rr) {
      int p = rr * 256 + tid;
      int row = p >> 4, c = p & 15;
      kreg[rr] = *(const uint4*)(kg + ((size_t)b * SS + t0 + row) * DD + c * 8);
    }
    __syncthreads();   // maskt/wacc staged (it0); previous tile reads done (it>0)
#pragma unroll
    for (int rr = 0; rr < 4; ++rr) {
      int p = rr * 256 + tid;
      int row = p >> 4, c = p & 15;
      int phys = c ^ (row & 7);
      *(uint4*)(kt + row * 256 + phys * 16) = kreg[rr];
    }
    __syncthreads();
#pragma unroll
    for (int nt = 0; nt < 4; ++nt) {
      int rb = nt * 16 + colL;
      bf16x8 bb[4];
#pragma unroll
      for (int kk = 0; kk < 4; ++kk) {
        int phys = (kk * 4 + quad) ^ (rb & 7);
        bb[kk] = *(const bf16x8*)(kt + rb * 256 + phys * 16);
      }
      int tl = kt0 * 64 + nt * 16 + colL;      // local t in 0..255
      int wl = tl >> 5, wb = tl & 31;
      float cs = 0.f;
#pragma unroll
      for (int mi = 0; mi < 2; ++mi) {
        f32x4 acc = {0.f, 0.f, 0.f, 0.f};
        acc = __builtin_amdgcn_mfma_f32_16x16x32_bf16(qf[mi][0], bb[0], acc, 0, 0, 0);
        acc = __builtin_amdgcn_mfma_f32_16x16x32_bf16(qf[mi][1], bb[1], acc, 0, 0, 0);
        acc = __builtin_amdgcn_mfma_f32_16x16x32_bf16(qf[mi][2], bb[2], acc, 0, 0, 0);
        acc = __builtin_amdgcn_mfma_f32_16x16x32_bf16(qf[mi][3], bb[3], acc, 0, 0, 0);
        int rbase = wv * 32 + mi * 16 + quad * 4;
#pragma unroll
        for (int r = 0; r < 4; ++r) {
          unsigned mw = maskt[(rbase + r) * 9 + wl];
          float e = ((mw >> wb) & 1u) ? 0.f : __expf(fminf(acc[r], 80.f));
          if (PZ) z[mi][r] += e;
          else cs += e * zinv[mi][r];
        }
      }
      if (!PZ) {
        cs += __shfl_xor(cs, 16, 64);
        cs += __shfl_xor(cs, 32, 64);
        if (quad == 0) atomicAdd(&wacc[tl], cs);
      }
    }
  }
  if (PZ) {
#pragma unroll
    for (int mi = 0; mi < 2; ++mi)
#pragma unroll
      for (int r = 0; r < 4; ++r) {
        float s = z[mi][r];
        s += __shfl_xor(s, 1, 64);
        s += __shfl_xor(s, 2, 64);
        s += __shfl_xor(s, 4, 64);
        s += __shfl_xor(s, 8, 64);
        if (colL == 0) {
          int row = row0 + wv * 32 + mi * 16 + quad * 4 + r;
          atomicAdd(&zg[(size_t)b * SS + row], s);
        }
      }
  } else {
    __syncthreads();
    atomicAdd(&wg[(size_t)b * SS + tbase + tid], wacc[tid]);
  }
}

// ---------------- y partials: y[b][d] = sum_t wg[b][t] * V[b][t][d] ----------------
__global__ __launch_bounds__(256) void k_yv(const float* __restrict__ wgl,
                                            const unsigned short* __restrict__ vg,
                                            float* __restrict__ ygl) {
  const int tid = threadIdx.x;
  const int tc = blockIdx.x, b = blockIdx.y;
  const int d = tid & 127, half = tid >> 7;
  const int t0 = tc * 128 + half * 64;
  float p = 0.f;
  const float* wrow = wgl + (size_t)b * SS + t0;
  const unsigned short* vrow = vg + ((size_t)b * SS + t0) * DD + d;
#pragma unroll 8
  for (int t = 0; t < 64; ++t) p += wrow[t] * bf2f(vrow[(size_t)t * DD]);
  atomicAdd(&ygl[b * DD + d], p);
}

// ---------------- out = (y/S) @ Wl + bl  (fp32 out) ----------------
__global__ __launch_bounds__(256) void k_out(const float* __restrict__ ygl,
                                             const float* __restrict__ Wl,
                                             const float* __restrict__ bl,
                                             float* __restrict__ outp) {
  __shared__ float ys[DD];
  const int tid = threadIdx.x;
  const int b = blockIdx.x;
  if (tid < DD) ys[tid] = ygl[b * DD + tid] * (1.0f / 2048.0f);
  __syncthreads();
  for (int c = tid; c < CC; c += 256) {
    float a = bl[c];
#pragma unroll 16
    for (int dd = 0; dd < DD; ++dd) a += ys[dd] * Wl[dd * CC + c];
    outp[b * CC + c] = a;
  }
}

extern "C" void kernel_launch(void* const* d_in, const int* in_sizes, int n_in,
                              void* d_out, int out_size, void* d_ws, size_t ws_size,
                              hipStream_t stream) {
  const void* ptr[10];
  for (int i = 0; i < 10; ++i) ptr[i] = (i < n_in) ? d_in[i] : nullptr;
  if (n_in == 10) {  // size-based slot matching (no-op under dict order)
    const void *px = 0, *pm = 0, *pWl = 0, *pbl = 0;
    const void* pW[3] = {0, 0, 0};
    const void* pb[3] = {0, 0, 0};
    int nW = 0, nb = 0;
    for (int i = 0; i < 10; ++i) {
      int s = in_sizes[i];
      if (s == 16777216) px = d_in[i];
      else if (s == 67108864) pm = d_in[i];
      else if (s == 128000) pWl = d_in[i];
      else if (s == 1000) pbl = d_in[i];
      else if (s == 65536 && nW < 3) pW[nW++] = d_in[i];
      else if (s == 128 && nb < 3) pb[nb++] = d_in[i];
    }
    if (px && pm && pWl && pbl && nW == 3 && nb == 3) {
      ptr[0] = px; ptr[1] = pm;
      ptr[2] = pW[0]; ptr[3] = pb[0];
      ptr[4] = pW[1]; ptr[5] = pb[1];
      ptr[6] = pW[2]; ptr[7] = pb[2];
      ptr[8] = pWl; ptr[9] = pbl;
    }
  }
  char* ws = (char*)d_ws;
  if (ws_size < (size_t)WS_END) return;
  int* flags = (int*)ws;
  float* wg = (float*)(ws + WS_WG);
  float* zg = (float*)(ws + WS_ZG);
  float* yg = (float*)(ws + WS_YG);
  unsigned* pk = (unsigned*)(ws + WS_PK);
  unsigned short* q  = (unsigned short*)(ws + WS_Q);
  unsigned short* k  = (unsigned short*)(ws + WS_K);
  unsigned short* v  = (unsigned short*)(ws + WS_V);
  unsigned short* wt = (unsigned short*)(ws + WS_WT);

  k_detect<<<1, 256, 0, stream>>>((const unsigned*)ptr[1], flags, wg, zg, yg);
  k_pack<<<32768, 256, 0, stream>>>(ptr[1], flags, pk);
  k_wt<<<768, 256, 0, stream>>>((const float*)ptr[2], (const float*)ptr[4],
                                (const float*)ptr[6], wt);
  k_proj<<<dim3(256, 3), 256, 0, stream>>>((const float*)ptr[0], wt,
                                           (const float*)ptr[3], (const float*)ptr[5],
                                           (const float*)ptr[7], q, k, v);
  k_attn2<true><<<dim3(16, 8, 16), 256, 0, stream>>>(q, k, pk, zg, wg);
  k_attn2<false><<<dim3(16, 8, 16), 256, 0, stream>>>(q, k, pk, zg, wg);
  k_yv<<<dim3(16, 16), 256, 0, stream>>>(wg, v, yg);
  k_out<<<16, 256, 0, stream>>>(yg, (const float*)ptr[8], (const float*)ptr[9],
                                (float*)d_out);
}